// Round 2
// baseline (3389.063 us; speedup 1.0000x reference)
//
#include <hip/hip_runtime.h>

// CharLSTM forward: B=16, T=256, H=1024, V=32000
//   P0 prep: fuse/transpose weights to bf16 (LDS tile transpose), embed gather, init state+barriers
//   P1 Gx = emb @ Wx_fused + b  (MFMA GEMM, out layout [T][4H][B])
//   P2 persistent recurrence: 1 kernel, 256 steps, grid barrier between steps;
//      Wh slice register-resident per wave, C-state register-resident per thread.
//   P3 Ys = Hs @ W_hq + b_q  (MFMA GEMM, out layout [B][T][V] f32 = d_out)

typedef __bf16 bf16_t;
typedef bf16_t bf16x8 __attribute__((ext_vector_type(8)));
typedef float f32x4 __attribute__((ext_vector_type(4)));
typedef unsigned short u16;
typedef unsigned int u32;

#define B_ 16
#define T_ 256
#define H_ 1024
#define V_ 32000
#define NBLK_R 32   // persistent-kernel grid

__device__ __forceinline__ u16 f2bf(float x) {
  union { float f; u32 u; } v; v.f = x;
  u32 r = v.u + 0x7FFFu + ((v.u >> 16) & 1u);
  return (u16)(r >> 16);
}

__device__ __forceinline__ bf16x8 ldb8(const u16* p) {
  return *reinterpret_cast<const bf16x8*>(p);
}

// ---------------- prep kernels ----------------

// grid 64 x 256: zero Hs[0], zero barriers, build fused bias
__global__ void k_init(u16* Hs0, unsigned* bar, float* bfu,
                       const float* b0, const float* b1, const float* b2, const float* b3) {
  int i = blockIdx.x * 256 + threadIdx.x;   // 16384 = B_*H_
  Hs0[i] = 0;
  if (i < T_) bar[i] = 0;
  if (i < 4096) {
    int g = i >> 10, u = i & 1023;
    const float* bb = (g == 0) ? b0 : (g == 1) ? b1 : (g == 2) ? b2 : b3;
    bfu[i] = bb[u];
  }
}

// emb_bf16[t*16+b][h] = bf16(embedding[ids[b][t]][h]); grid 4096 x 256
__global__ void k_embed(const int* __restrict__ ids, const float* __restrict__ emb,
                        u16* __restrict__ out) {
  int r = blockIdx.x;               // r = t*16 + b
  int t = r >> 4, b = r & 15;
  int row = ids[b * T_ + t];
  const f32x4 v = *(const f32x4*)&emb[(size_t)row * H_ + threadIdx.x * 4];
  ushort4 o;
  o.x = f2bf(v[0]); o.y = f2bf(v[1]); o.z = f2bf(v[2]); o.w = f2bf(v[3]);
  *(ushort4*)&out[(size_t)r * H_ + threadIdx.x * 4] = o;
}

// WT[g*1024 + u][k] = bf16(W_g[k][u]) via LDS 64x64 tile transpose. grid (16,16,4) x 256
__global__ void k_fuse4(const float* __restrict__ W0, const float* __restrict__ W1,
                        const float* __restrict__ W2, const float* __restrict__ W3,
                        u16* __restrict__ WT) {
  __shared__ float ti[64][65];
  int g = blockIdx.z;
  const float* W = (g == 0) ? W0 : (g == 1) ? W1 : (g == 2) ? W2 : W3;
  int u0 = blockIdx.x * 64, k0 = blockIdx.y * 64;
  int c = threadIdx.x & 63, rq = threadIdx.x >> 6;
#pragma unroll
  for (int p = 0; p < 16; ++p) {
    int rr = p * 4 + rq;
    ti[rr][c] = W[(size_t)(k0 + rr) * H_ + u0 + c];
  }
  __syncthreads();
#pragma unroll
  for (int p = 0; p < 16; ++p) {
    int uu = p * 4 + rq;
    WT[(size_t)(g * H_ + u0 + uu) * H_ + k0 + c] = f2bf(ti[c][uu]);
  }
}

// WqT[n][k] = bf16(Whq[k][n]) via LDS 64x64 tile transpose. grid (500, 16) x 256
__global__ void k_transq(const float* __restrict__ Whq, u16* __restrict__ WqT) {
  __shared__ float ti[64][65];
  int n0 = blockIdx.x * 64, k0 = blockIdx.y * 64;
  int c = threadIdx.x & 63, rq = threadIdx.x >> 6;
#pragma unroll
  for (int p = 0; p < 16; ++p) {
    int rr = p * 4 + rq;
    ti[rr][c] = Whq[(size_t)(k0 + rr) * V_ + n0 + c];
  }
  __syncthreads();
#pragma unroll
  for (int p = 0; p < 16; ++p) {
    int nn = p * 4 + rq;
    WqT[(size_t)(n0 + nn) * H_ + k0 + c] = f2bf(ti[c][nn]);
  }
}

// ---------------- MFMA GEMM (128x128 tile, 4 waves, reg-staged LDS) ----------------
// C = A[M][K] * Bt[N][K]^T + bias[n]
// MODE 0: out[(t*N + n)*16 + b], row r = t*16+b   -> Gx layout [T][4H][B]
// MODE 1: out[b*(T_*V_) + t*V_ + n]               -> Ys layout [B][T][V]
template <int MODE>
__global__ __launch_bounds__(256)
void gemm128(const u16* __restrict__ A, const u16* __restrict__ Bt,
             const float* __restrict__ bias, float* __restrict__ out,
             int M, int N, int K) {
  __shared__ u16 As[128 * 40];
  __shared__ u16 Bs[128 * 40];
  const int tid = threadIdx.x;
  const int l = tid & 63, w = tid >> 6;
  const int m0 = blockIdx.y * 128, n0 = blockIdx.x * 128;
  const int wm = (w & 1) * 64, wn = (w >> 1) * 64;
  const int koff = (l >> 4) * 8;

  f32x4 acc[4][4] = {};

  for (int k0 = 0; k0 < K; k0 += 32) {
#pragma unroll
    for (int c = tid; c < 512; c += 256) {
      int mm = c >> 2, kk = (c & 3) * 8;
      *(uint4*)&As[mm * 40 + kk] = *(const uint4*)&A[(size_t)(m0 + mm) * K + k0 + kk];
      *(uint4*)&Bs[mm * 40 + kk] = *(const uint4*)&Bt[(size_t)(n0 + mm) * K + k0 + kk];
    }
    __syncthreads();
    bf16x8 af[4], bfr[4];
#pragma unroll
    for (int tm = 0; tm < 4; ++tm)
      af[tm] = ldb8(&As[(wm + tm * 16 + (l & 15)) * 40 + koff]);
#pragma unroll
    for (int tn = 0; tn < 4; ++tn)
      bfr[tn] = ldb8(&Bs[(wn + tn * 16 + (l & 15)) * 40 + koff]);
#pragma unroll
    for (int tm = 0; tm < 4; ++tm)
#pragma unroll
      for (int tn = 0; tn < 4; ++tn)
        acc[tm][tn] = __builtin_amdgcn_mfma_f32_16x16x32_bf16(af[tm], bfr[tn], acc[tm][tn], 0, 0, 0);
    __syncthreads();
  }

#pragma unroll
  for (int tm = 0; tm < 4; ++tm) {
    int rbase = m0 + wm + tm * 16 + (l >> 4) * 4;
    int t = rbase >> 4;
    int bb = rbase & 15;
#pragma unroll
    for (int tn = 0; tn < 4; ++tn) {
      int n = n0 + wn + tn * 16 + (l & 15);
      float bv = bias[n];
      if (MODE == 0) {
        f32x4 v = acc[tm][tn];
        v[0] += bv; v[1] += bv; v[2] += bv; v[3] += bv;
        *(f32x4*)&out[((size_t)t * N + n) * 16 + bb] = v;
      } else {
#pragma unroll
        for (int j = 0; j < 4; ++j) {
          out[(size_t)(bb + j) * ((size_t)T_ * V_) + (size_t)t * V_ + n] = acc[tm][tn][j] + bv;
        }
      }
    }
  }
}

// ---------------- persistent LSTM recurrence ----------------
// 32 blocks x 512 thr = 256 waves. Wave gw owns hidden units [gw*4, gw*4+4).
// Wh slice lives in registers (32 bf16x8 b-frags/lane); C-state lives in a register.
// Grid barrier (device-scope atomics) between steps.
__global__ __launch_bounds__(512, 1)
void lstm_persist(const u16* __restrict__ WhT, const float* __restrict__ Gx,
                  u16* __restrict__ Hs, unsigned* __restrict__ bar,
                  float* __restrict__ outH, float* __restrict__ outC) {
  __shared__ float gx[8][16][16];
  const int tid = threadIdx.x, l = tid & 63, w = tid >> 6;
  const int gw = blockIdx.x * 8 + w;            // 0..255
  const int hu0 = gw * 4;
  const int c = l & 15;                          // gate g = c>>2, local unit = c&3
  const int n = (c >> 2) * H_ + hu0 + (c & 3);   // fused gate column
  const int koff = (l >> 4) * 8;
  const int m = l & 15, u = l >> 4;              // epilogue: batch m, local unit u
  const int hu = hu0 + u;

  // preload Wh b-fragments: 32 x bf16x8 = 128 VGPRs, resident for all 256 steps
  bf16x8 bq[32];
  {
    const u16* bp = WhT + (size_t)n * H_ + koff;
#pragma unroll
    for (int kk = 0; kk < 32; ++kk) bq[kk] = ldb8(bp + kk * 32);
  }

  float Cs = 0.0f;   // register-resident cell state for (m, hu)

  for (int t = 0; t < T_; ++t) {
    const f32x4 g4 = *(const f32x4*)&Gx[((size_t)t * 4096 + n) * 16 + (size_t)(l >> 4) * 4];
    const u16* ap = Hs + (size_t)t * (B_ * H_) + (size_t)(l & 15) * H_ + koff;

    f32x4 a0 = {}, a1 = {}, a2 = {}, a3 = {};
#pragma unroll
    for (int kk = 0; kk < 32; kk += 4) {
      a0 = __builtin_amdgcn_mfma_f32_16x16x32_bf16(ldb8(ap + (kk + 0) * 32), bq[kk + 0], a0, 0, 0, 0);
      a1 = __builtin_amdgcn_mfma_f32_16x16x32_bf16(ldb8(ap + (kk + 1) * 32), bq[kk + 1], a1, 0, 0, 0);
      a2 = __builtin_amdgcn_mfma_f32_16x16x32_bf16(ldb8(ap + (kk + 2) * 32), bq[kk + 2], a2, 0, 0, 0);
      a3 = __builtin_amdgcn_mfma_f32_16x16x32_bf16(ldb8(ap + (kk + 3) * 32), bq[kk + 3], a3, 0, 0, 0);
    }
    f32x4 acc = (a0 + a1) + (a2 + a3);

#pragma unroll
    for (int j = 0; j < 4; ++j)
      gx[w][(l >> 4) * 4 + j][c] = acc[j] + g4[j];
    __syncthreads();

    float gi = gx[w][m][0 + u];
    float gf = gx[w][m][4 + u];
    float go = gx[w][m][8 + u];
    float gc = gx[w][m][12 + u];
    float I = 1.0f / (1.0f + expf(-gi));
    float F = 1.0f / (1.0f + expf(-gf));
    float O = 1.0f / (1.0f + expf(-go));
    float Ct = tanhf(gc);
    Cs = F * Cs + I * Ct;
    float Hn = O * tanhf(Cs);
    Hs[(size_t)(t + 1) * (B_ * H_) + (size_t)m * H_ + hu] = f2bf(Hn);
    if (t == T_ - 1) {
      outH[(size_t)m * H_ + hu] = Hn;
      outC[(size_t)m * H_ + hu] = Cs;
    }

    // grid barrier: release H stores, wait for all blocks, acquire fresh H
    __syncthreads();                                   // drains vmcnt(0) for all waves
    if (tid == 0) {
      __hip_atomic_fetch_add(&bar[t], 1u, __ATOMIC_RELEASE, __HIP_MEMORY_SCOPE_AGENT);
      while (__hip_atomic_load(&bar[t], __ATOMIC_ACQUIRE, __HIP_MEMORY_SCOPE_AGENT) < NBLK_R) {
        __builtin_amdgcn_s_sleep(2);
      }
    }
    __syncthreads();
  }
}

// ---------------- host launcher ----------------

extern "C" void kernel_launch(void* const* d_in, const int* in_sizes, int n_in,
                              void* d_out, int out_size, void* d_ws, size_t ws_size,
                              hipStream_t stream) {
  const int*   ids = (const int*)d_in[0];
  const float* emb = (const float*)d_in[1];
  const float* Wxi = (const float*)d_in[2];
  const float* Whi = (const float*)d_in[3];
  const float* bi  = (const float*)d_in[4];
  const float* Wxf = (const float*)d_in[5];
  const float* Whf = (const float*)d_in[6];
  const float* bfv = (const float*)d_in[7];
  const float* Wxo = (const float*)d_in[8];
  const float* Who = (const float*)d_in[9];
  const float* bo  = (const float*)d_in[10];
  const float* Wxc = (const float*)d_in[11];
  const float* Whc = (const float*)d_in[12];
  const float* bc  = (const float*)d_in[13];
  const float* Whq = (const float*)d_in[14];
  const float* bq  = (const float*)d_in[15];
  float* out = (float*)d_out;

  char* ws = (char*)d_ws;
  u16* WxT = (u16*)ws;      ws += (size_t)4096 * H_ * 2;          // 8.4 MB
  u16* WhT = (u16*)ws;      ws += (size_t)4096 * H_ * 2;          // 8.4 MB
  u16* WqT = (u16*)ws;      ws += (size_t)V_ * H_ * 2;            // 65.5 MB
  u16* Emb = (u16*)ws;      ws += (size_t)T_ * B_ * H_ * 2;       // 8.4 MB
  float* Gx = (float*)ws;   ws += (size_t)T_ * 4096 * B_ * 4;     // 67 MB
  u16* Hs  = (u16*)ws;      ws += (size_t)(T_ + 1) * B_ * H_ * 2; // 8.4 MB
  float* bfu = (float*)ws;  ws += (size_t)4096 * 4;
  unsigned* bar = (unsigned*)ws; ws += (size_t)T_ * 4;

  // P0: prep
  k_init<<<64, 256, 0, stream>>>(Hs, bar, bfu, bi, bfv, bo, bc);
  k_embed<<<4096, 256, 0, stream>>>(ids, emb, Emb);
  k_fuse4<<<dim3(16, 16, 4), 256, 0, stream>>>(Wxi, Wxf, Wxo, Wxc, WxT);
  k_fuse4<<<dim3(16, 16, 4), 256, 0, stream>>>(Whi, Whf, Who, Whc, WhT);
  k_transq<<<dim3(500, 16), 256, 0, stream>>>(Whq, WqT);

  // P1: Gx = emb @ Wx + b   (M=4096, N=4096, K=1024)
  gemm128<0><<<dim3(32, 32), 256, 0, stream>>>(Emb, WxT, bfu, Gx, 4096, 4096, H_);

  // P2: persistent recurrence (single launch, 256 steps)
  float* outH = out + (size_t)B_ * T_ * V_;
  float* outC = outH + (size_t)B_ * H_;
  lstm_persist<<<NBLK_R, 512, 0, stream>>>(WhT, Gx, Hs, bar, outH, outC);

  // P3: Ys = Hs[1..T] @ W_hq + b_q  (M=4096, N=32000, K=1024)
  gemm128<1><<<dim3(250, 32), 256, 0, stream>>>(Hs + (size_t)B_ * H_, WqT, bq, out, 4096, V_, H_);
}

// Round 3
// 3204.385 us; speedup vs baseline: 1.0576x; 1.0576x over previous
//
#include <hip/hip_runtime.h>

// CharLSTM forward: B=16, T=256, H=1024, V=32000
//   P0 prep: fuse/transpose weights to bf16, embed gather, init state+counter
//   P1 Gx = emb @ Wx_fused + b  (MFMA GEMM, out layout [T][4H][B])
//   P2 persistent recurrence: 1 kernel, 256 steps; fence-free step sync:
//      H written via relaxed agent atomics (write-through to MALL), plain reads
//      (write-once/read-once addresses => no stale local copies), monotonic
//      global counter barrier with LDS front end. No __syncthreads in loop.
//   P3 Ys = Hs @ W_hq + b_q  (MFMA GEMM, out layout [B][T][V] f32 = d_out)

typedef __bf16 bf16_t;
typedef bf16_t bf16x8 __attribute__((ext_vector_type(8)));
typedef float f32x4 __attribute__((ext_vector_type(4)));
typedef unsigned short u16;
typedef unsigned int u32;

#define B_ 16
#define T_ 256
#define H_ 1024
#define V_ 32000
#define NBLK_R 32   // persistent-kernel grid (8 waves each => 256 waves)

__device__ __forceinline__ u16 f2bf(float x) {
  union { float f; u32 u; } v; v.f = x;
  u32 r = v.u + 0x7FFFu + ((v.u >> 16) & 1u);
  return (u16)(r >> 16);
}

__device__ __forceinline__ bf16x8 ldb8(const u16* p) {
  return *reinterpret_cast<const bf16x8*>(p);
}

// fast sigmoid / tanh (v_exp + v_rcp); |arg| clamped, gates are O(1)
__device__ __forceinline__ float fsig(float x) {
  return __builtin_amdgcn_rcpf(1.0f + __expf(-x));
}
__device__ __forceinline__ float ftanh(float x) {
  float x2 = fminf(fmaxf(2.0f * x, -80.0f), 80.0f);
  float e = __expf(x2);
  return (e - 1.0f) * __builtin_amdgcn_rcpf(e + 1.0f);
}

// ---------------- prep kernels ----------------

// grid 64 x 256: zero Hs[0], zero global counter, build fused bias
__global__ void k_init(u16* Hs0, unsigned* gbar, float* bfu,
                       const float* b0, const float* b1, const float* b2, const float* b3) {
  int i = blockIdx.x * 256 + threadIdx.x;   // 16384 = B_*H_
  Hs0[i] = 0;
  if (i < 8) gbar[i] = 0;
  if (i < 4096) {
    int g = i >> 10, u = i & 1023;
    const float* bb = (g == 0) ? b0 : (g == 1) ? b1 : (g == 2) ? b2 : b3;
    bfu[i] = bb[u];
  }
}

// emb_bf16[t*16+b][h] = bf16(embedding[ids[b][t]][h]); grid 4096 x 256
__global__ void k_embed(const int* __restrict__ ids, const float* __restrict__ emb,
                        u16* __restrict__ out) {
  int r = blockIdx.x;               // r = t*16 + b
  int t = r >> 4, b = r & 15;
  int row = ids[b * T_ + t];
  const f32x4 v = *(const f32x4*)&emb[(size_t)row * H_ + threadIdx.x * 4];
  ushort4 o;
  o.x = f2bf(v[0]); o.y = f2bf(v[1]); o.z = f2bf(v[2]); o.w = f2bf(v[3]);
  *(ushort4*)&out[(size_t)r * H_ + threadIdx.x * 4] = o;
}

// WT[g*1024 + u][k] = bf16(W_g[k][u]) via LDS 64x64 tile transpose. grid (16,16,4) x 256
__global__ void k_fuse4(const float* __restrict__ W0, const float* __restrict__ W1,
                        const float* __restrict__ W2, const float* __restrict__ W3,
                        u16* __restrict__ WT) {
  __shared__ float ti[64][65];
  int g = blockIdx.z;
  const float* W = (g == 0) ? W0 : (g == 1) ? W1 : (g == 2) ? W2 : W3;
  int u0 = blockIdx.x * 64, k0 = blockIdx.y * 64;
  int c = threadIdx.x & 63, rq = threadIdx.x >> 6;
#pragma unroll
  for (int p = 0; p < 16; ++p) {
    int rr = p * 4 + rq;
    ti[rr][c] = W[(size_t)(k0 + rr) * H_ + u0 + c];
  }
  __syncthreads();
#pragma unroll
  for (int p = 0; p < 16; ++p) {
    int uu = p * 4 + rq;
    WT[(size_t)(g * H_ + u0 + uu) * H_ + k0 + c] = f2bf(ti[c][uu]);
  }
}

// WqT[n][k] = bf16(Whq[k][n]) via LDS 64x64 tile transpose. grid (500, 16) x 256
__global__ void k_transq(const float* __restrict__ Whq, u16* __restrict__ WqT) {
  __shared__ float ti[64][65];
  int n0 = blockIdx.x * 64, k0 = blockIdx.y * 64;
  int c = threadIdx.x & 63, rq = threadIdx.x >> 6;
#pragma unroll
  for (int p = 0; p < 16; ++p) {
    int rr = p * 4 + rq;
    ti[rr][c] = Whq[(size_t)(k0 + rr) * V_ + n0 + c];
  }
  __syncthreads();
#pragma unroll
  for (int p = 0; p < 16; ++p) {
    int nn = p * 4 + rq;
    WqT[(size_t)(n0 + nn) * H_ + k0 + c] = f2bf(ti[c][nn]);
  }
}

// ---------------- MFMA GEMM (128x128 tile, 4 waves, reg-staged LDS) ----------------
// C = A[M][K] * Bt[N][K]^T + bias[n]
// MODE 0: out[(t*N + n)*16 + b], row r = t*16+b   -> Gx layout [T][4H][B]
// MODE 1: out[b*(T_*V_) + t*V_ + n]               -> Ys layout [B][T][V]
template <int MODE>
__global__ __launch_bounds__(256)
void gemm128(const u16* __restrict__ A, const u16* __restrict__ Bt,
             const float* __restrict__ bias, float* __restrict__ out,
             int M, int N, int K) {
  __shared__ u16 As[128 * 40];
  __shared__ u16 Bs[128 * 40];
  const int tid = threadIdx.x;
  const int l = tid & 63, w = tid >> 6;
  const int m0 = blockIdx.y * 128, n0 = blockIdx.x * 128;
  const int wm = (w & 1) * 64, wn = (w >> 1) * 64;
  const int koff = (l >> 4) * 8;

  f32x4 acc[4][4] = {};

  for (int k0 = 0; k0 < K; k0 += 32) {
#pragma unroll
    for (int c = tid; c < 512; c += 256) {
      int mm = c >> 2, kk = (c & 3) * 8;
      *(uint4*)&As[mm * 40 + kk] = *(const uint4*)&A[(size_t)(m0 + mm) * K + k0 + kk];
      *(uint4*)&Bs[mm * 40 + kk] = *(const uint4*)&Bt[(size_t)(n0 + mm) * K + k0 + kk];
    }
    __syncthreads();
    bf16x8 af[4], bfr[4];
#pragma unroll
    for (int tm = 0; tm < 4; ++tm)
      af[tm] = ldb8(&As[(wm + tm * 16 + (l & 15)) * 40 + koff]);
#pragma unroll
    for (int tn = 0; tn < 4; ++tn)
      bfr[tn] = ldb8(&Bs[(wn + tn * 16 + (l & 15)) * 40 + koff]);
#pragma unroll
    for (int tm = 0; tm < 4; ++tm)
#pragma unroll
      for (int tn = 0; tn < 4; ++tn)
        acc[tm][tn] = __builtin_amdgcn_mfma_f32_16x16x32_bf16(af[tm], bfr[tn], acc[tm][tn], 0, 0, 0);
    __syncthreads();
  }

#pragma unroll
  for (int tm = 0; tm < 4; ++tm) {
    int rbase = m0 + wm + tm * 16 + (l >> 4) * 4;
    int t = rbase >> 4;
    int bb = rbase & 15;
#pragma unroll
    for (int tn = 0; tn < 4; ++tn) {
      int n = n0 + wn + tn * 16 + (l & 15);
      float bv = bias[n];
      if (MODE == 0) {
        f32x4 v = acc[tm][tn];
        v[0] += bv; v[1] += bv; v[2] += bv; v[3] += bv;
        *(f32x4*)&out[((size_t)t * N + n) * 16 + bb] = v;
      } else {
#pragma unroll
        for (int j = 0; j < 4; ++j) {
          out[(size_t)(bb + j) * ((size_t)T_ * V_) + (size_t)t * V_ + n] = acc[tm][tn][j] + bv;
        }
      }
    }
  }
}

// ---------------- persistent LSTM recurrence (fence-free sync) ----------------
// 32 blocks x 512 thr = 256 waves. Wave gw owns hidden units [gw*4, gw*4+4).
// Wh slice register-resident; C-state register-resident.
// Per step: plain H loads -> MFMA -> wave-local LDS transpose -> gates ->
// write-through atomic H stores -> vmcnt(0) -> LDS arrive -> global arrive.
__global__ __launch_bounds__(512, 1)
void lstm_persist(const u16* __restrict__ WhT, const float* __restrict__ Gx,
                  u16* __restrict__ Hs, unsigned* __restrict__ gbar,
                  float* __restrict__ outH, float* __restrict__ outC) {
  __shared__ float gx[8][16][16];
  __shared__ unsigned lbar;
  const int tid = threadIdx.x, l = tid & 63, w = tid >> 6;
  const int gw = blockIdx.x * 8 + w;            // 0..255
  const int hu0 = gw * 4;
  const int c = l & 15;                          // gate g = c>>2, local unit = c&3
  const int n = (c >> 2) * H_ + hu0 + (c & 3);   // fused gate column
  const int koff = (l >> 4) * 8;
  const int m = l & 15, u = l >> 4;              // epilogue: batch m, local unit u
  const int hu = hu0 + u;

  if (tid == 0) lbar = 0;
  __syncthreads();

  // preload Wh b-fragments: 32 x bf16x8, resident for all 256 steps
  bf16x8 bq[32];
  {
    const u16* bp = WhT + (size_t)n * H_ + koff;
#pragma unroll
    for (int kk = 0; kk < 32; ++kk) bq[kk] = ldb8(bp + kk * 32);
  }

  float Cs = 0.0f;
  u32* HsU32 = (u32*)Hs;

  for (int t = 0; t < T_; ++t) {
    // Gx[t] is barrier-independent: issue before the spin
    const f32x4 g4 = *(const f32x4*)&Gx[((size_t)t * 4096 + n) * 16 + (size_t)(l >> 4) * 4];

    if (t > 0) {
      const unsigned tgt = (unsigned)NBLK_R * (unsigned)t;
      if (l == 0) {
        while (__hip_atomic_load(gbar, __ATOMIC_RELAXED, __HIP_MEMORY_SCOPE_AGENT) < tgt)
          __builtin_amdgcn_s_sleep(4);
      }
      asm volatile("" ::: "memory");   // compiler barrier: keep H loads below the spin
    }

    const u16* ap = Hs + (size_t)t * (B_ * H_) + (size_t)m * H_ + koff;
    f32x4 a0 = {}, a1 = {}, a2 = {}, a3 = {};
#pragma unroll
    for (int kk = 0; kk < 32; kk += 4) {
      a0 = __builtin_amdgcn_mfma_f32_16x16x32_bf16(ldb8(ap + (kk + 0) * 32), bq[kk + 0], a0, 0, 0, 0);
      a1 = __builtin_amdgcn_mfma_f32_16x16x32_bf16(ldb8(ap + (kk + 1) * 32), bq[kk + 1], a1, 0, 0, 0);
      a2 = __builtin_amdgcn_mfma_f32_16x16x32_bf16(ldb8(ap + (kk + 2) * 32), bq[kk + 2], a2, 0, 0, 0);
      a3 = __builtin_amdgcn_mfma_f32_16x16x32_bf16(ldb8(ap + (kk + 3) * 32), bq[kk + 3], a3, 0, 0, 0);
    }
    f32x4 acc = (a0 + a1) + (a2 + a3);

    // wave-local LDS transpose (gx[w] is private to wave w; lgkmcnt ordering only)
#pragma unroll
    for (int j = 0; j < 4; ++j)
      gx[w][(l >> 4) * 4 + j][c] = acc[j] + g4[j];

    float gi = gx[w][m][0 + u];
    float gf = gx[w][m][4 + u];
    float go = gx[w][m][8 + u];
    float gc = gx[w][m][12 + u];
    float I = fsig(gi);
    float F = fsig(gf);
    float O = fsig(go);
    float Ct = ftanh(gc);
    Cs = F * Cs + I * Ct;
    float Hn = O * ftanh(Cs);

    // pack 2 bf16 per u32, store write-through to MALL (relaxed agent atomic)
    u32 hb = (u32)f2bf(Hn);
    u32 other = __shfl_down(hb, 16);             // lane(u) gets lane(u+1)'s value
    if (!(u & 1)) {
      size_t eidx = (size_t)(t + 1) * (B_ * H_) + (size_t)m * H_ + hu;  // even
      __hip_atomic_store(&HsU32[eidx >> 1], hb | (other << 16),
                         __ATOMIC_RELAXED, __HIP_MEMORY_SCOPE_AGENT);
    }
    if (t == T_ - 1) {
      outH[(size_t)m * H_ + hu] = Hn;
      outC[(size_t)m * H_ + hu] = Cs;
    }

    // arrive: own stores at MALL first, then LDS counter, 8th wave bumps global
    asm volatile("s_waitcnt vmcnt(0)" ::: "memory");
    if (l == 0) {
      unsigned old = __hip_atomic_fetch_add(&lbar, 1u, __ATOMIC_RELAXED,
                                            __HIP_MEMORY_SCOPE_WORKGROUP);
      if (old == (unsigned)(8 * t + 7))
        __hip_atomic_fetch_add(gbar, 1u, __ATOMIC_RELAXED, __HIP_MEMORY_SCOPE_AGENT);
    }
  }
}

// ---------------- host launcher ----------------

extern "C" void kernel_launch(void* const* d_in, const int* in_sizes, int n_in,
                              void* d_out, int out_size, void* d_ws, size_t ws_size,
                              hipStream_t stream) {
  const int*   ids = (const int*)d_in[0];
  const float* emb = (const float*)d_in[1];
  const float* Wxi = (const float*)d_in[2];
  const float* Whi = (const float*)d_in[3];
  const float* bi  = (const float*)d_in[4];
  const float* Wxf = (const float*)d_in[5];
  const float* Whf = (const float*)d_in[6];
  const float* bfv = (const float*)d_in[7];
  const float* Wxo = (const float*)d_in[8];
  const float* Who = (const float*)d_in[9];
  const float* bo  = (const float*)d_in[10];
  const float* Wxc = (const float*)d_in[11];
  const float* Whc = (const float*)d_in[12];
  const float* bc  = (const float*)d_in[13];
  const float* Whq = (const float*)d_in[14];
  const float* bq  = (const float*)d_in[15];
  float* out = (float*)d_out;

  char* ws = (char*)d_ws;
  u16* WxT = (u16*)ws;      ws += (size_t)4096 * H_ * 2;          // 8.4 MB
  u16* WhT = (u16*)ws;      ws += (size_t)4096 * H_ * 2;          // 8.4 MB
  u16* WqT = (u16*)ws;      ws += (size_t)V_ * H_ * 2;            // 65.5 MB
  u16* Emb = (u16*)ws;      ws += (size_t)T_ * B_ * H_ * 2;       // 8.4 MB
  float* Gx = (float*)ws;   ws += (size_t)T_ * 4096 * B_ * 4;     // 67 MB
  u16* Hs  = (u16*)ws;      ws += (size_t)(T_ + 1) * B_ * H_ * 2; // 8.4 MB
  float* bfu = (float*)ws;  ws += (size_t)4096 * 4;
  unsigned* gbar = (unsigned*)ws; ws += 256 * 4;

  // P0: prep
  k_init<<<64, 256, 0, stream>>>(Hs, gbar, bfu, bi, bfv, bo, bc);
  k_embed<<<4096, 256, 0, stream>>>(ids, emb, Emb);
  k_fuse4<<<dim3(16, 16, 4), 256, 0, stream>>>(Wxi, Wxf, Wxo, Wxc, WxT);
  k_fuse4<<<dim3(16, 16, 4), 256, 0, stream>>>(Whi, Whf, Who, Whc, WhT);
  k_transq<<<dim3(500, 16), 256, 0, stream>>>(Whq, WqT);

  // P1: Gx = emb @ Wx + b   (M=4096, N=4096, K=1024)
  gemm128<0><<<dim3(32, 32), 256, 0, stream>>>(Emb, WxT, bfu, Gx, 4096, 4096, H_);

  // P2: persistent recurrence (single launch, 256 steps)
  float* outH = out + (size_t)B_ * T_ * V_;
  float* outC = outH + (size_t)B_ * H_;
  lstm_persist<<<NBLK_R, 512, 0, stream>>>(WhT, Gx, Hs, gbar, outH, outC);

  // P3: Ys = Hs[1..T] @ W_hq + b_q  (M=4096, N=32000, K=1024)
  gemm128<1><<<dim3(250, 32), 256, 0, stream>>>(Hs + (size_t)B_ * H_, WqT, bq, out, 4096, V_, H_);
}

// Round 4
// 2863.626 us; speedup vs baseline: 1.1835x; 1.1190x over previous
//
#include <hip/hip_runtime.h>

// CharLSTM forward: B=16, T=256, H=1024, V=32000
//   P0 prep: fuse/transpose weights to bf16, embed gather, init state+counter
//   P1 Gx = emb @ Wx_fused + b  (MFMA GEMM, out layout [T][4H][B])
//   P2 persistent recurrence: 1 kernel, 256 steps. Sync per step:
//      u64-packed relaxed-agent atomic H stores (write-through to MALL),
//      vmcnt(0)+__syncthreads, tid0 fetch_add on global counter, tid0 polls
//      (32 pollers chip-wide), __syncthreads broadcast. Plain H loads are safe:
//      each Hs step-region is written once, read after the barrier, 128B lines
//      never span steps, caches invalidated at kernel launch.
//   P3 Ys = Hs @ W_hq + b_q  (MFMA GEMM, out layout [B][T][V] f32 = d_out)

typedef __bf16 bf16_t;
typedef bf16_t bf16x8 __attribute__((ext_vector_type(8)));
typedef float f32x4 __attribute__((ext_vector_type(4)));
typedef unsigned short u16;
typedef unsigned int u32;
typedef unsigned long long u64;

#define B_ 16
#define T_ 256
#define H_ 1024
#define V_ 32000
#define NBLK_R 32   // persistent-kernel grid (8 waves each => 256 waves)

__device__ __forceinline__ u16 f2bf(float x) {
  union { float f; u32 u; } v; v.f = x;
  u32 r = v.u + 0x7FFFu + ((v.u >> 16) & 1u);
  return (u16)(r >> 16);
}

__device__ __forceinline__ bf16x8 ldb8(const u16* p) {
  return *reinterpret_cast<const bf16x8*>(p);
}

// fast sigmoid / tanh (v_exp + v_rcp)
__device__ __forceinline__ float fsig(float x) {
  return __builtin_amdgcn_rcpf(1.0f + __expf(-x));
}
__device__ __forceinline__ float ftanh(float x) {
  float x2 = fminf(fmaxf(2.0f * x, -80.0f), 80.0f);
  float e = __expf(x2);
  return (e - 1.0f) * __builtin_amdgcn_rcpf(e + 1.0f);
}

// ---------------- prep kernels ----------------

// grid 64 x 256: zero Hs[0], zero global counter, build fused bias
__global__ void k_init(u16* Hs0, unsigned* gbar, float* bfu,
                       const float* b0, const float* b1, const float* b2, const float* b3) {
  int i = blockIdx.x * 256 + threadIdx.x;   // 16384 = B_*H_
  Hs0[i] = 0;
  if (i < 8) gbar[i] = 0;
  if (i < 4096) {
    int g = i >> 10, u = i & 1023;
    const float* bb = (g == 0) ? b0 : (g == 1) ? b1 : (g == 2) ? b2 : b3;
    bfu[i] = bb[u];
  }
}

// emb_bf16[t*16+b][h] = bf16(embedding[ids[b][t]][h]); grid 4096 x 256
__global__ void k_embed(const int* __restrict__ ids, const float* __restrict__ emb,
                        u16* __restrict__ out) {
  int r = blockIdx.x;               // r = t*16 + b
  int t = r >> 4, b = r & 15;
  int row = ids[b * T_ + t];
  const f32x4 v = *(const f32x4*)&emb[(size_t)row * H_ + threadIdx.x * 4];
  ushort4 o;
  o.x = f2bf(v[0]); o.y = f2bf(v[1]); o.z = f2bf(v[2]); o.w = f2bf(v[3]);
  *(ushort4*)&out[(size_t)r * H_ + threadIdx.x * 4] = o;
}

// WT[g*1024 + u][k] = bf16(W_g[k][u]) via LDS 64x64 tile transpose. grid (16,16,4) x 256
__global__ void k_fuse4(const float* __restrict__ W0, const float* __restrict__ W1,
                        const float* __restrict__ W2, const float* __restrict__ W3,
                        u16* __restrict__ WT) {
  __shared__ float ti[64][65];
  int g = blockIdx.z;
  const float* W = (g == 0) ? W0 : (g == 1) ? W1 : (g == 2) ? W2 : W3;
  int u0 = blockIdx.x * 64, k0 = blockIdx.y * 64;
  int c = threadIdx.x & 63, rq = threadIdx.x >> 6;
#pragma unroll
  for (int p = 0; p < 16; ++p) {
    int rr = p * 4 + rq;
    ti[rr][c] = W[(size_t)(k0 + rr) * H_ + u0 + c];
  }
  __syncthreads();
#pragma unroll
  for (int p = 0; p < 16; ++p) {
    int uu = p * 4 + rq;
    WT[(size_t)(g * H_ + u0 + uu) * H_ + k0 + c] = f2bf(ti[c][uu]);
  }
}

// WqT[n][k] = bf16(Whq[k][n]) via LDS 64x64 tile transpose. grid (500, 16) x 256
__global__ void k_transq(const float* __restrict__ Whq, u16* __restrict__ WqT) {
  __shared__ float ti[64][65];
  int n0 = blockIdx.x * 64, k0 = blockIdx.y * 64;
  int c = threadIdx.x & 63, rq = threadIdx.x >> 6;
#pragma unroll
  for (int p = 0; p < 16; ++p) {
    int rr = p * 4 + rq;
    ti[rr][c] = Whq[(size_t)(k0 + rr) * V_ + n0 + c];
  }
  __syncthreads();
#pragma unroll
  for (int p = 0; p < 16; ++p) {
    int nn = p * 4 + rq;
    WqT[(size_t)(n0 + nn) * H_ + k0 + c] = f2bf(ti[c][nn]);
  }
}

// ---------------- MFMA GEMM (128x128 tile, 4 waves, reg-staged LDS) ----------------
// C = A[M][K] * Bt[N][K]^T + bias[n]
// MODE 0: out[(t*N + n)*16 + b], row r = t*16+b   -> Gx layout [T][4H][B]
// MODE 1: out[b*(T_*V_) + t*V_ + n]               -> Ys layout [B][T][V]
template <int MODE>
__global__ __launch_bounds__(256)
void gemm128(const u16* __restrict__ A, const u16* __restrict__ Bt,
             const float* __restrict__ bias, float* __restrict__ out,
             int M, int N, int K) {
  __shared__ u16 As[128 * 40];
  __shared__ u16 Bs[128 * 40];
  const int tid = threadIdx.x;
  const int l = tid & 63, w = tid >> 6;
  const int m0 = blockIdx.y * 128, n0 = blockIdx.x * 128;
  const int wm = (w & 1) * 64, wn = (w >> 1) * 64;
  const int koff = (l >> 4) * 8;

  f32x4 acc[4][4] = {};

  for (int k0 = 0; k0 < K; k0 += 32) {
#pragma unroll
    for (int c = tid; c < 512; c += 256) {
      int mm = c >> 2, kk = (c & 3) * 8;
      *(uint4*)&As[mm * 40 + kk] = *(const uint4*)&A[(size_t)(m0 + mm) * K + k0 + kk];
      *(uint4*)&Bs[mm * 40 + kk] = *(const uint4*)&Bt[(size_t)(n0 + mm) * K + k0 + kk];
    }
    __syncthreads();
    bf16x8 af[4], bfr[4];
#pragma unroll
    for (int tm = 0; tm < 4; ++tm)
      af[tm] = ldb8(&As[(wm + tm * 16 + (l & 15)) * 40 + koff]);
#pragma unroll
    for (int tn = 0; tn < 4; ++tn)
      bfr[tn] = ldb8(&Bs[(wn + tn * 16 + (l & 15)) * 40 + koff]);
#pragma unroll
    for (int tm = 0; tm < 4; ++tm)
#pragma unroll
      for (int tn = 0; tn < 4; ++tn)
        acc[tm][tn] = __builtin_amdgcn_mfma_f32_16x16x32_bf16(af[tm], bfr[tn], acc[tm][tn], 0, 0, 0);
    __syncthreads();
  }

#pragma unroll
  for (int tm = 0; tm < 4; ++tm) {
    int rbase = m0 + wm + tm * 16 + (l >> 4) * 4;
    int t = rbase >> 4;
    int bb = rbase & 15;
#pragma unroll
    for (int tn = 0; tn < 4; ++tn) {
      int n = n0 + wn + tn * 16 + (l & 15);
      float bv = bias[n];
      if (MODE == 0) {
        f32x4 v = acc[tm][tn];
        v[0] += bv; v[1] += bv; v[2] += bv; v[3] += bv;
        *(f32x4*)&out[((size_t)t * N + n) * 16 + bb] = v;
      } else {
#pragma unroll
        for (int j = 0; j < 4; ++j) {
          out[(size_t)(bb + j) * ((size_t)T_ * V_) + (size_t)t * V_ + n] = acc[tm][tn][j] + bv;
        }
      }
    }
  }
}

// ---------------- persistent LSTM recurrence ----------------
// 32 blocks x 512 thr = 256 waves. Wave gw owns hidden units [gw*4, gw*4+4).
// Wh slice register-resident; C-state register-resident.
__global__ __launch_bounds__(512, 1)
void lstm_persist(const u16* __restrict__ WhT, const float* __restrict__ Gx,
                  u16* __restrict__ Hs, unsigned* __restrict__ gbar,
                  float* __restrict__ outH, float* __restrict__ outC) {
  __shared__ float gx[8][16][16];
  const int tid = threadIdx.x, l = tid & 63, w = tid >> 6;
  const int gw = blockIdx.x * 8 + w;            // 0..255
  const int hu0 = gw * 4;
  const int c = l & 15;                          // gate g = c>>2, local unit = c&3
  const int n = (c >> 2) * H_ + hu0 + (c & 3);   // fused gate column
  const int koff = (l >> 4) * 8;
  const int m = l & 15, u = l >> 4;              // epilogue: batch m, local unit u
  const int hu = hu0 + u;

  // preload Wh b-fragments: 32 x bf16x8, resident for all 256 steps
  bf16x8 bq[32];
  {
    const u16* bp = WhT + (size_t)n * H_ + koff;
#pragma unroll
    for (int kk = 0; kk < 32; ++kk) bq[kk] = ldb8(bp + kk * 32);
  }

  float Cs = 0.0f;
  u64* HsU64 = (u64*)Hs;

  for (int t = 0; t < T_; ++t) {
    // Gx[t] is barrier-independent: issue before the wait
    const f32x4 g4 = *(const f32x4*)&Gx[((size_t)t * 4096 + n) * 16 + (size_t)(l >> 4) * 4];

    if (t > 0) {
      if (tid == 0) {
        const unsigned tgt = (unsigned)NBLK_R * (unsigned)t;
        while (__hip_atomic_load(gbar, __ATOMIC_RELAXED, __HIP_MEMORY_SCOPE_AGENT) < tgt)
          __builtin_amdgcn_s_sleep(1);
      }
      __syncthreads();   // broadcast "step t inputs ready" to all 8 waves
    }

    const u16* ap = Hs + (size_t)t * (B_ * H_) + (size_t)m * H_ + koff;
    f32x4 a0 = {}, a1 = {}, a2 = {}, a3 = {};
#pragma unroll
    for (int kk = 0; kk < 32; kk += 4) {
      a0 = __builtin_amdgcn_mfma_f32_16x16x32_bf16(ldb8(ap + (kk + 0) * 32), bq[kk + 0], a0, 0, 0, 0);
      a1 = __builtin_amdgcn_mfma_f32_16x16x32_bf16(ldb8(ap + (kk + 1) * 32), bq[kk + 1], a1, 0, 0, 0);
      a2 = __builtin_amdgcn_mfma_f32_16x16x32_bf16(ldb8(ap + (kk + 2) * 32), bq[kk + 2], a2, 0, 0, 0);
      a3 = __builtin_amdgcn_mfma_f32_16x16x32_bf16(ldb8(ap + (kk + 3) * 32), bq[kk + 3], a3, 0, 0, 0);
    }
    f32x4 acc = (a0 + a1) + (a2 + a3);

    // wave-local LDS transpose (gx[w] private to wave w; lgkmcnt ordering only)
#pragma unroll
    for (int j = 0; j < 4; ++j)
      gx[w][(l >> 4) * 4 + j][c] = acc[j] + g4[j];

    float gi = gx[w][m][0 + u];
    float gf = gx[w][m][4 + u];
    float go = gx[w][m][8 + u];
    float gc = gx[w][m][12 + u];
    float I = fsig(gi);
    float F = fsig(gf);
    float O = fsig(go);
    float Ct = ftanh(gc);
    Cs = F * Cs + I * Ct;
    float Hn = O * ftanh(Cs);

    // pack 4 bf16 (units hu0..hu0+3 of batch m) into one u64, store write-through
    u32 hb = (u32)f2bf(Hn);
    u32 h1 = __shfl_down(hb, 16);
    u32 h2 = __shfl_down(hb, 32);
    u32 h3 = __shfl_down(hb, 48);
    if (l < 16) {
      u64 pk = (u64)hb | ((u64)h1 << 16) | ((u64)h2 << 32) | ((u64)h3 << 48);
      __hip_atomic_store(&HsU64[(size_t)(t + 1) * 4096 + (size_t)m * 256 + gw], pk,
                         __ATOMIC_RELAXED, __HIP_MEMORY_SCOPE_AGENT);
    }

    if (t == T_ - 1) {
      outH[(size_t)m * H_ + hu] = Hn;
      outC[(size_t)m * H_ + hu] = Cs;
    } else {
      // drain stores (syncthreads also waits vmcnt(0) per wave), then arrive
      asm volatile("s_waitcnt vmcnt(0)" ::: "memory");
      __syncthreads();
      if (tid == 0)
        __hip_atomic_fetch_add(gbar, 1u, __ATOMIC_RELAXED, __HIP_MEMORY_SCOPE_AGENT);
    }
  }
}

// ---------------- host launcher ----------------

extern "C" void kernel_launch(void* const* d_in, const int* in_sizes, int n_in,
                              void* d_out, int out_size, void* d_ws, size_t ws_size,
                              hipStream_t stream) {
  const int*   ids = (const int*)d_in[0];
  const float* emb = (const float*)d_in[1];
  const float* Wxi = (const float*)d_in[2];
  const float* Whi = (const float*)d_in[3];
  const float* bi  = (const float*)d_in[4];
  const float* Wxf = (const float*)d_in[5];
  const float* Whf = (const float*)d_in[6];
  const float* bfv = (const float*)d_in[7];
  const float* Wxo = (const float*)d_in[8];
  const float* Who = (const float*)d_in[9];
  const float* bo  = (const float*)d_in[10];
  const float* Wxc = (const float*)d_in[11];
  const float* Whc = (const float*)d_in[12];
  const float* bc  = (const float*)d_in[13];
  const float* Whq = (const float*)d_in[14];
  const float* bq  = (const float*)d_in[15];
  float* out = (float*)d_out;

  char* ws = (char*)d_ws;
  u16* WxT = (u16*)ws;      ws += (size_t)4096 * H_ * 2;          // 8.4 MB
  u16* WhT = (u16*)ws;      ws += (size_t)4096 * H_ * 2;          // 8.4 MB
  u16* WqT = (u16*)ws;      ws += (size_t)V_ * H_ * 2;            // 65.5 MB
  u16* Emb = (u16*)ws;      ws += (size_t)T_ * B_ * H_ * 2;       // 8.4 MB
  float* Gx = (float*)ws;   ws += (size_t)T_ * 4096 * B_ * 4;     // 67 MB
  u16* Hs  = (u16*)ws;      ws += (size_t)(T_ + 1) * B_ * H_ * 2; // 8.4 MB
  float* bfu = (float*)ws;  ws += (size_t)4096 * 4;
  unsigned* gbar = (unsigned*)ws; ws += 256 * 4;

  // P0: prep
  k_init<<<64, 256, 0, stream>>>(Hs, gbar, bfu, bi, bfv, bo, bc);
  k_embed<<<4096, 256, 0, stream>>>(ids, emb, Emb);
  k_fuse4<<<dim3(16, 16, 4), 256, 0, stream>>>(Wxi, Wxf, Wxo, Wxc, WxT);
  k_fuse4<<<dim3(16, 16, 4), 256, 0, stream>>>(Whi, Whf, Who, Whc, WhT);
  k_transq<<<dim3(500, 16), 256, 0, stream>>>(Whq, WqT);

  // P1: Gx = emb @ Wx + b   (M=4096, N=4096, K=1024)
  gemm128<0><<<dim3(32, 32), 256, 0, stream>>>(Emb, WxT, bfu, Gx, 4096, 4096, H_);

  // P2: persistent recurrence (single launch, 256 steps)
  float* outH = out + (size_t)B_ * T_ * V_;
  float* outC = outH + (size_t)B_ * H_;
  lstm_persist<<<NBLK_R, 512, 0, stream>>>(WhT, Gx, Hs, gbar, outH, outC);

  // P3: Ys = Hs[1..T] @ W_hq + b_q  (M=4096, N=32000, K=1024)
  gemm128<1><<<dim3(250, 32), 256, 0, stream>>>(Hs + (size_t)B_ * H_, WqT, bq, out, 4096, V_, H_);
}

// Round 6
// 2861.063 us; speedup vs baseline: 1.1845x; 1.0009x over previous
//
#include <hip/hip_runtime.h>

// CharLSTM forward: B=16, T=256, H=1024, V=32000
//   P0 prep: fuse/transpose weights to bf16, embed gather, init state + flags
//   P1 Gx = emb @ Wx_fused + b  (MFMA GEMM, out layout [T][4H][B])
//   P2 persistent recurrence: 32 blocks x 512 thr, 256 steps. Step sync via
//      FLAG ARRAY (one padded line per block, monotonic step values): arrive =
//      1 relaxed-agent atomic store, detect = 32 parallel line reads + __all.
//      No same-address RMW anywhere on the step critical path.
//      H exchange: u64-packed relaxed-agent atomic stores (write-through, MALL),
//      plain loads (first-touch lines => always fresh). Proven in round 4.
//   P3 Ys = Hs @ W_hq + b_q  (MFMA GEMM, out layout [B][T][V] f32 = d_out)

typedef __bf16 bf16_t;
typedef bf16_t bf16x8 __attribute__((ext_vector_type(8)));
typedef float f32x4 __attribute__((ext_vector_type(4)));
typedef unsigned short u16;
typedef unsigned int u32;
typedef unsigned long long u64;

#define B_ 16
#define T_ 256
#define H_ 1024
#define V_ 32000
#define NBLK_R 32   // persistent-kernel grid (8 waves each => 256 waves)
#define FLAG_STRIDE 16  // u32s per flag slot = 64B line padding

__device__ __forceinline__ u16 f2bf(float x) {
  union { float f; u32 u; } v; v.f = x;
  u32 r = v.u + 0x7FFFu + ((v.u >> 16) & 1u);
  return (u16)(r >> 16);
}

__device__ __forceinline__ bf16x8 ldb8(const u16* p) {
  return *reinterpret_cast<const bf16x8*>(p);
}

// fast sigmoid / tanh (v_exp + v_rcp)
__device__ __forceinline__ float fsig(float x) {
  return __builtin_amdgcn_rcpf(1.0f + __expf(-x));
}
__device__ __forceinline__ float ftanh(float x) {
  float x2 = fminf(fmaxf(2.0f * x, -80.0f), 80.0f);
  float e = __expf(x2);
  return (e - 1.0f) * __builtin_amdgcn_rcpf(e + 1.0f);
}

// ---------------- prep kernels ----------------

// grid 64 x 256: zero Hs[0], zero done-flags, build fused bias
__global__ void k_init(u32* Hs0u32, u32* done, float* bfu,
                       const float* b0, const float* b1, const float* b2, const float* b3) {
  int i = blockIdx.x * 256 + threadIdx.x;   // 16384
  if (i < 8192)   // Hs[0]: 16384 bf16 = 8192 u32
    __hip_atomic_store(&Hs0u32[i], 0u, __ATOMIC_RELAXED, __HIP_MEMORY_SCOPE_AGENT);
  if (i < NBLK_R * FLAG_STRIDE)
    __hip_atomic_store(&done[i], 0u, __ATOMIC_RELAXED, __HIP_MEMORY_SCOPE_AGENT);
  if (i < 4096) {
    int g = i >> 10, u = i & 1023;
    const float* bb = (g == 0) ? b0 : (g == 1) ? b1 : (g == 2) ? b2 : b3;
    bfu[i] = bb[u];
  }
}

// emb_bf16[t*16+b][h] = bf16(embedding[ids[b][t]][h]); grid 4096 x 256
__global__ void k_embed(const int* __restrict__ ids, const float* __restrict__ emb,
                        u16* __restrict__ out) {
  int r = blockIdx.x;               // r = t*16 + b
  int t = r >> 4, b = r & 15;
  int row = ids[b * T_ + t];
  const f32x4 v = *(const f32x4*)&emb[(size_t)row * H_ + threadIdx.x * 4];
  ushort4 o;
  o.x = f2bf(v[0]); o.y = f2bf(v[1]); o.z = f2bf(v[2]); o.w = f2bf(v[3]);
  *(ushort4*)&out[(size_t)r * H_ + threadIdx.x * 4] = o;
}

// WT[g*1024 + u][k] = bf16(W_g[k][u]) via LDS 64x64 tile transpose. grid (16,16,4) x 256
__global__ void k_fuse4(const float* __restrict__ W0, const float* __restrict__ W1,
                        const float* __restrict__ W2, const float* __restrict__ W3,
                        u16* __restrict__ WT) {
  __shared__ float ti[64][65];
  int g = blockIdx.z;
  const float* W = (g == 0) ? W0 : (g == 1) ? W1 : (g == 2) ? W2 : W3;
  int u0 = blockIdx.x * 64, k0 = blockIdx.y * 64;
  int c = threadIdx.x & 63, rq = threadIdx.x >> 6;
#pragma unroll
  for (int p = 0; p < 16; ++p) {
    int rr = p * 4 + rq;
    ti[rr][c] = W[(size_t)(k0 + rr) * H_ + u0 + c];
  }
  __syncthreads();
#pragma unroll
  for (int p = 0; p < 16; ++p) {
    int uu = p * 4 + rq;
    WT[(size_t)(g * H_ + u0 + uu) * H_ + k0 + c] = f2bf(ti[c][uu]);
  }
}

// WqT[n][k] = bf16(Whq[k][n]) via LDS 64x64 tile transpose. grid (500, 16) x 256
__global__ void k_transq(const float* __restrict__ Whq, u16* __restrict__ WqT) {
  __shared__ float ti[64][65];
  int n0 = blockIdx.x * 64, k0 = blockIdx.y * 64;
  int c = threadIdx.x & 63, rq = threadIdx.x >> 6;
#pragma unroll
  for (int p = 0; p < 16; ++p) {
    int rr = p * 4 + rq;
    ti[rr][c] = Whq[(size_t)(k0 + rr) * V_ + n0 + c];
  }
  __syncthreads();
#pragma unroll
  for (int p = 0; p < 16; ++p) {
    int nn = p * 4 + rq;
    WqT[(size_t)(n0 + nn) * H_ + k0 + c] = f2bf(ti[c][nn]);
  }
}

// ---------------- MFMA GEMM (128x128 tile, 4 waves, reg-staged LDS) ----------------
// C = A[M][K] * Bt[N][K]^T + bias[n]
// MODE 0: out[(t*N + n)*16 + b], row r = t*16+b   -> Gx layout [T][4H][B]
// MODE 1: out[b*(T_*V_) + t*V_ + n]               -> Ys layout [B][T][V]
template <int MODE>
__global__ __launch_bounds__(256)
void gemm128(const u16* __restrict__ A, const u16* __restrict__ Bt,
             const float* __restrict__ bias, float* __restrict__ out,
             int M, int N, int K) {
  __shared__ u16 As[128 * 40];
  __shared__ u16 Bs[128 * 40];
  const int tid = threadIdx.x;
  const int l = tid & 63, w = tid >> 6;
  const int m0 = blockIdx.y * 128, n0 = blockIdx.x * 128;
  const int wm = (w & 1) * 64, wn = (w >> 1) * 64;
  const int koff = (l >> 4) * 8;

  f32x4 acc[4][4] = {};

  for (int k0 = 0; k0 < K; k0 += 32) {
#pragma unroll
    for (int c = tid; c < 512; c += 256) {
      int mm = c >> 2, kk = (c & 3) * 8;
      *(uint4*)&As[mm * 40 + kk] = *(const uint4*)&A[(size_t)(m0 + mm) * K + k0 + kk];
      *(uint4*)&Bs[mm * 40 + kk] = *(const uint4*)&Bt[(size_t)(n0 + mm) * K + k0 + kk];
    }
    __syncthreads();
    bf16x8 af[4], bfr[4];
#pragma unroll
    for (int tm = 0; tm < 4; ++tm)
      af[tm] = ldb8(&As[(wm + tm * 16 + (l & 15)) * 40 + koff]);
#pragma unroll
    for (int tn = 0; tn < 4; ++tn)
      bfr[tn] = ldb8(&Bs[(wn + tn * 16 + (l & 15)) * 40 + koff]);
#pragma unroll
    for (int tm = 0; tm < 4; ++tm)
#pragma unroll
      for (int tn = 0; tn < 4; ++tn)
        acc[tm][tn] = __builtin_amdgcn_mfma_f32_16x16x32_bf16(af[tm], bfr[tn], acc[tm][tn], 0, 0, 0);
    __syncthreads();
  }

#pragma unroll
  for (int tm = 0; tm < 4; ++tm) {
    int rbase = m0 + wm + tm * 16 + (l >> 4) * 4;
    int t = rbase >> 4;
    int bb = rbase & 15;
#pragma unroll
    for (int tn = 0; tn < 4; ++tn) {
      int n = n0 + wn + tn * 16 + (l & 15);
      float bv = bias[n];
      if (MODE == 0) {
        f32x4 v = acc[tm][tn];
        v[0] += bv; v[1] += bv; v[2] += bv; v[3] += bv;
        *(f32x4*)&out[((size_t)t * N + n) * 16 + bb] = v;
      } else {
#pragma unroll
        for (int j = 0; j < 4; ++j) {
          out[(size_t)(bb + j) * ((size_t)T_ * V_) + (size_t)t * V_ + n] = acc[tm][tn][j] + bv;
        }
      }
    }
  }
}

// ---------------- persistent LSTM recurrence (flag-array barrier) ----------------
// 32 blocks x 512 thr = 256 waves. Wave gw owns hidden units [gw*4, gw*4+4).
// Wh slice register-resident; C-state register-resident.
// done[blk] (64B-padded) holds the last completed step+1, monotonic.
__global__ __launch_bounds__(512, 1)
void lstm_persist(const u16* __restrict__ WhT, const float* __restrict__ Gx,
                  u16* __restrict__ Hs, u32* __restrict__ done,
                  float* __restrict__ outH, float* __restrict__ outC) {
  __shared__ float gx[8][16][16];
  const int tid = threadIdx.x, l = tid & 63, w = tid >> 6;
  const int gw = blockIdx.x * 8 + w;            // 0..255
  const int hu0 = gw * 4;
  const int c = l & 15;                          // gate g = c>>2, local unit = c&3
  const int n = (c >> 2) * H_ + hu0 + (c & 3);   // fused gate column
  const int koff = (l >> 4) * 8;
  const int m = l & 15, u = l >> 4;              // epilogue: batch m, local unit u
  const int hu = hu0 + u;

  // preload Wh b-fragments: 32 x bf16x8, resident for all 256 steps
  bf16x8 bq[32];
  {
    const u16* bp = WhT + (size_t)n * H_ + koff;
#pragma unroll
    for (int kk = 0; kk < 32; ++kk) bq[kk] = ldb8(bp + kk * 32);
  }

  float Cs = 0.0f;
  u64* HsU64 = (u64*)Hs;
  const u32* myflag = &done[(l & 31) * FLAG_STRIDE];

  for (int t = 0; t < T_; ++t) {
    // Gx[t] is barrier-independent: issue before the wait
    const f32x4 g4 = *(const f32x4*)&Gx[((size_t)t * 4096 + n) * 16 + (size_t)(l >> 4) * 4];

    if (t > 0) {
      if (w == 0) {
        // lanes watch the 32 per-block flags (32 distinct lines, parallel reads)
        while (true) {
          u32 v = __hip_atomic_load(myflag, __ATOMIC_RELAXED, __HIP_MEMORY_SCOPE_AGENT);
          if (__all((int)(v >= (u32)t))) break;
          __builtin_amdgcn_s_sleep(1);
        }
      }
      __syncthreads();   // broadcast "step t inputs ready" to all 8 waves
    }

    const u16* ap = Hs + (size_t)t * (B_ * H_) + (size_t)m * H_ + koff;
    f32x4 a0 = {}, a1 = {}, a2 = {}, a3 = {};
#pragma unroll
    for (int kk = 0; kk < 32; kk += 4) {
      a0 = __builtin_amdgcn_mfma_f32_16x16x32_bf16(ldb8(ap + (kk + 0) * 32), bq[kk + 0], a0, 0, 0, 0);
      a1 = __builtin_amdgcn_mfma_f32_16x16x32_bf16(ldb8(ap + (kk + 1) * 32), bq[kk + 1], a1, 0, 0, 0);
      a2 = __builtin_amdgcn_mfma_f32_16x16x32_bf16(ldb8(ap + (kk + 2) * 32), bq[kk + 2], a2, 0, 0, 0);
      a3 = __builtin_amdgcn_mfma_f32_16x16x32_bf16(ldb8(ap + (kk + 3) * 32), bq[kk + 3], a3, 0, 0, 0);
    }
    f32x4 acc = (a0 + a1) + (a2 + a3);

    // wave-local LDS transpose (gx[w] private to wave w; lgkmcnt ordering only)
#pragma unroll
    for (int j = 0; j < 4; ++j)
      gx[w][(l >> 4) * 4 + j][c] = acc[j] + g4[j];

    float gi = gx[w][m][0 + u];
    float gf = gx[w][m][4 + u];
    float go = gx[w][m][8 + u];
    float gc = gx[w][m][12 + u];
    float I = fsig(gi);
    float F = fsig(gf);
    float O = fsig(go);
    float Ct = ftanh(gc);
    Cs = F * Cs + I * Ct;
    float Hn = O * ftanh(Cs);

    // pack 4 bf16 (units hu0..hu0+3 of batch m) into one u64, store write-through
    u32 hb = (u32)f2bf(Hn);
    u32 h1 = __shfl_down(hb, 16);
    u32 h2 = __shfl_down(hb, 32);
    u32 h3 = __shfl_down(hb, 48);
    if (l < 16) {
      u64 pk = (u64)hb | ((u64)h1 << 16) | ((u64)h2 << 32) | ((u64)h3 << 48);
      __hip_atomic_store(&HsU64[(size_t)(t + 1) * 4096 + (size_t)m * 256 + gw], pk,
                         __ATOMIC_RELAXED, __HIP_MEMORY_SCOPE_AGENT);
    }

    if (t == T_ - 1) {
      outH[(size_t)m * H_ + hu] = Hn;
      outC[(size_t)m * H_ + hu] = Cs;
    } else {
      // own H stores acked at MALL, block-wide, then ONE flag store (no RMW)
      asm volatile("s_waitcnt vmcnt(0)" ::: "memory");
      __syncthreads();
      if (tid == 0)
        __hip_atomic_store(&done[blockIdx.x * FLAG_STRIDE], (u32)(t + 1),
                           __ATOMIC_RELAXED, __HIP_MEMORY_SCOPE_AGENT);
    }
  }
}

// ---------------- host launcher ----------------

extern "C" void kernel_launch(void* const* d_in, const int* in_sizes, int n_in,
                              void* d_out, int out_size, void* d_ws, size_t ws_size,
                              hipStream_t stream) {
  const int*   ids = (const int*)d_in[0];
  const float* emb = (const float*)d_in[1];
  const float* Wxi = (const float*)d_in[2];
  const float* Whi = (const float*)d_in[3];
  const float* bi  = (const float*)d_in[4];
  const float* Wxf = (const float*)d_in[5];
  const float* Whf = (const float*)d_in[6];
  const float* bfv = (const float*)d_in[7];
  const float* Wxo = (const float*)d_in[8];
  const float* Who = (const float*)d_in[9];
  const float* bo  = (const float*)d_in[10];
  const float* Wxc = (const float*)d_in[11];
  const float* Whc = (const float*)d_in[12];
  const float* bc  = (const float*)d_in[13];
  const float* Whq = (const float*)d_in[14];
  const float* bq  = (const float*)d_in[15];
  float* out = (float*)d_out;

  char* ws = (char*)d_ws;
  u16* WxT = (u16*)ws;      ws += (size_t)4096 * H_ * 2;          // 8.4 MB
  u16* WhT = (u16*)ws;      ws += (size_t)4096 * H_ * 2;          // 8.4 MB
  u16* WqT = (u16*)ws;      ws += (size_t)V_ * H_ * 2;            // 65.5 MB
  u16* Emb = (u16*)ws;      ws += (size_t)T_ * B_ * H_ * 2;       // 8.4 MB
  float* Gx = (float*)ws;   ws += (size_t)T_ * 4096 * B_ * 4;     // 67 MB
  u16* Hs  = (u16*)ws;      ws += (size_t)(T_ + 1) * B_ * H_ * 2; // 8.4 MB
  float* bfu = (float*)ws;  ws += (size_t)4096 * 4;
  u32* done = (u32*)ws;     ws += (size_t)NBLK_R * FLAG_STRIDE * 4;

  // P0: prep
  k_init<<<64, 256, 0, stream>>>((u32*)Hs, done, bfu, bi, bfv, bo, bc);
  k_embed<<<4096, 256, 0, stream>>>(ids, emb, Emb);
  k_fuse4<<<dim3(16, 16, 4), 256, 0, stream>>>(Wxi, Wxf, Wxo, Wxc, WxT);
  k_fuse4<<<dim3(16, 16, 4), 256, 0, stream>>>(Whi, Whf, Who, Whc, WhT);
  k_transq<<<dim3(500, 16), 256, 0, stream>>>(Whq, WqT);

  // P1: Gx = emb @ Wx + b   (M=4096, N=4096, K=1024)
  gemm128<0><<<dim3(32, 32), 256, 0, stream>>>(Emb, WxT, bfu, Gx, 4096, 4096, H_);

  // P2: persistent recurrence (single launch, 256 steps)
  float* outH = out + (size_t)B_ * T_ * V_;
  float* outC = outH + (size_t)B_ * H_;
  lstm_persist<<<NBLK_R, 512, 0, stream>>>(WhT, Gx, Hs, done, outH, outC);

  // P3: Ys = Hs[1..T] @ W_hq + b_q  (M=4096, N=32000, K=1024)
  gemm128<1><<<dim3(250, 32), 256, 0, stream>>>(Hs + (size_t)B_ * H_, WqT, bq, out, 4096, V_, H_);
}